// Round 3
// baseline (222.190 us; speedup 1.0000x reference)
//
#include <hip/hip_runtime.h>

// YOLO-v1 loss, N=4096, S=14 grid, 30 channels/cell. ~176 MB in, 5 floats out.
// R1: killed same-line atomicAdd fan-in (188us serialized chain).
// R2: killed LDS staging + both barriers. Cell rows (120 B) are 8B-aligned ->
//     direct float2 loads; consecutive lanes = consecutive cells so every
//     fetched line is fully consumed. Max occupancy, deep MLP per wave.

#define NBATCH   4096
#define CELLS    (NBATCH * 14 * 14)       // 802816
#define THREADS  256
#define NBLK     784                      // 784*256*4 == CELLS exactly
#define CPT      4                        // cells per thread
#define TSTRIDE  (NBLK * THREADS)         // 200704
#define L_COORD  5.0f
#define L_NOOBJ  0.5f

__global__ __launch_bounds__(THREADS, 8) void yolo_main(
    const float* __restrict__ pred,    // [CELLS][30]
    const float* __restrict__ tbox,    // [CELLS][4]
    const float* __restrict__ tcls,    // [CELLS][20]
    const int*   __restrict__ objmap,  // [CELLS]
    float4*      __restrict__ part)    // [NBLK]
{
    const int tid = threadIdx.x;
    const int g0  = blockIdx.x * THREADS + tid;

    float acc_reg = 0.f, acc_cont = 0.f, acc_noobj = 0.f, acc_cls = 0.f;
    const float invS = 1.0f / 14.0f;

    #pragma unroll
    for (int it = 0; it < CPT; ++it) {
        const int c = g0 + it * TSTRIDE;

        const float2* p2 = (const float2*)pred + (size_t)c * 15;  // 120B row, 8B aligned
        // box floats 0..9
        float2 f0 = p2[0], f1 = p2[1], f2 = p2[2], f3 = p2[3], f4 = p2[4];
        float4 tb = ((const float4*)tbox)[c];
        float  o  = objmap[c] ? 1.0f : 0.0f;

        // ---- cls: pred floats 10..29 vs tcls float4 x5 ----
        {
            const float4* t4 = (const float4*)tcls + (size_t)c * 5;
            float cl = 0.f;
            #pragma unroll
            for (int j = 0; j < 5; ++j) {
                float4 t  = t4[j];
                float2 a  = p2[5 + 2 * j];
                float2 b  = p2[6 + 2 * j];
                float d0 = a.x - t.x, d1 = a.y - t.y;
                float d2 = b.x - t.z, d3 = b.y - t.w;
                cl += d0 * d0 + d1 * d1 + d2 * d2 + d3 * d3;
            }
            acc_cls += o * cl;
        }

        // ---- boxes / iou / noobj ----
        float x1 = f0.x, y1 = f0.y, w1 = f1.x, h1 = f1.y, c1 = f2.x;
        float x2 = f2.y, y2 = f3.x, w2 = f3.y, h2 = f4.x, c2 = f4.y;

        acc_noobj += (1.0f - o) * (c1 * c1 + c2 * c2);

        float txc = tb.x * invS, tyc = tb.y * invS;
        float tx1 = txc - 0.5f * tb.z, ty1 = tyc - 0.5f * tb.w;
        float tx2 = txc + 0.5f * tb.z, ty2 = tyc + 0.5f * tb.w;
        float ta  = (tx2 - tx1) * (ty2 - ty1);

        float ax1 = x1 * invS - 0.5f * w1, ay1 = y1 * invS - 0.5f * h1;
        float ax2 = x1 * invS + 0.5f * w1, ay2 = y1 * invS + 0.5f * h1;
        float a1  = (ax2 - ax1) * (ay2 - ay1);
        float iw  = fmaxf(fminf(ax2, tx2) - fmaxf(ax1, tx1), 0.f);
        float ih  = fmaxf(fminf(ay2, ty2) - fmaxf(ay1, ty1), 0.f);
        float inter1 = iw * ih;
        float iou1   = inter1 / (a1 + ta - inter1);

        float bx1 = x2 * invS - 0.5f * w2, by1 = y2 * invS - 0.5f * h2;
        float bx2 = x2 * invS + 0.5f * w2, by2 = y2 * invS + 0.5f * h2;
        float a2  = (bx2 - bx1) * (by2 - by1);
        float jw  = fmaxf(fminf(bx2, tx2) - fmaxf(bx1, tx1), 0.f);
        float jh  = fmaxf(fminf(by2, ty2) - fmaxf(by1, ty1), 0.f);
        float inter2 = jw * jh;
        float iou2   = inter2 / (a2 + ta - inter2);

        bool  t1   = iou1 > iou2;
        float bx   = t1 ? x1 : x2,  by = t1 ? y1 : y2;
        float bw   = t1 ? w1 : w2,  bh = t1 ? h1 : h2;
        float bc   = t1 ? c1 : c2;
        float biou = t1 ? iou1 : iou2;

        float dx = bx - tb.x, dy = by - tb.y;
        float dw = sqrtf(bw) - sqrtf(tb.z);
        float dh = sqrtf(bh) - sqrtf(tb.w);
        acc_reg  += o * (dx * dx + dy * dy + dw * dw + dh * dh);
        float dc  = bc - biou;
        acc_cont += o * dc * dc;
    }

    // ---- block reduction: wave shuffle -> LDS -> one float4 store ----
    __shared__ float red[4][4];
    #pragma unroll
    for (int off = 32; off > 0; off >>= 1) {
        acc_reg   += __shfl_down(acc_reg,   off);
        acc_cont  += __shfl_down(acc_cont,  off);
        acc_noobj += __shfl_down(acc_noobj, off);
        acc_cls   += __shfl_down(acc_cls,   off);
    }
    const int wave = tid >> 6, lane = tid & 63;
    if (lane == 0) {
        red[wave][0] = acc_reg;
        red[wave][1] = acc_cont;
        red[wave][2] = acc_noobj;
        red[wave][3] = acc_cls;
    }
    __syncthreads();
    if (tid == 0) {
        float4 p;
        p.x = red[0][0] + red[1][0] + red[2][0] + red[3][0];
        p.y = red[0][1] + red[1][1] + red[2][1] + red[3][1];
        p.z = red[0][2] + red[1][2] + red[2][2] + red[3][2];
        p.w = red[0][3] + red[1][3] + red[2][3] + red[3][3];
        part[blockIdx.x] = p;
    }
}

__global__ __launch_bounds__(1024) void yolo_reduce(
    const float4* __restrict__ part, float* __restrict__ out)
{
    __shared__ float red[16][4];
    float r = 0.f, c = 0.f, n = 0.f, cl = 0.f;
    if (threadIdx.x < NBLK) {            // one load per thread, no chain
        float4 p = part[threadIdx.x];
        r = p.x; c = p.y; n = p.z; cl = p.w;
    }
    #pragma unroll
    for (int off = 32; off > 0; off >>= 1) {
        r  += __shfl_down(r,  off);
        c  += __shfl_down(c,  off);
        n  += __shfl_down(n,  off);
        cl += __shfl_down(cl, off);
    }
    const int wave = threadIdx.x >> 6, lane = threadIdx.x & 63;
    if (lane == 0) {
        red[wave][0] = r; red[wave][1] = c; red[wave][2] = n; red[wave][3] = cl;
    }
    __syncthreads();
    if (threadIdx.x == 0) {
        float R = 0.f, C = 0.f, Nn = 0.f, Cl = 0.f;
        #pragma unroll
        for (int w = 0; w < 16; ++w) {
            R += red[w][0]; C += red[w][1]; Nn += red[w][2]; Cl += red[w][3];
        }
        const float invN = 1.0f / (float)NBATCH;
        float reg   = L_COORD * R  * invN;
        float cont  =           C  * invN;
        float noobj = L_NOOBJ * Nn * invN;
        float cls   =           Cl * invN;
        out[0] = reg + cont + noobj + cls;
        out[1] = reg;
        out[2] = cont;
        out[3] = noobj;
        out[4] = cls;
    }
}

extern "C" void kernel_launch(void* const* d_in, const int* in_sizes, int n_in,
                              void* d_out, int out_size, void* d_ws, size_t ws_size,
                              hipStream_t stream) {
    const float* pred   = (const float*)d_in[0];
    const float* tbox   = (const float*)d_in[1];
    const float* tcls   = (const float*)d_in[2];
    const int*   objmap = (const int*)  d_in[3];
    float4* part = (float4*)d_ws;      // NBLK * 16 B, every slot written
    float*  out  = (float*)d_out;

    yolo_main<<<NBLK, THREADS, 0, stream>>>(pred, tbox, tcls, objmap, part);
    yolo_reduce<<<1, 1024, 0, stream>>>(part, out);
}

// Round 4
// 207.731 us; speedup vs baseline: 1.0696x; 1.0696x over previous
//
#include <hip/hip_runtime.h>

// YOLO-v1 loss, N=4096, S=14 grid, 30 channels/cell. ~176 MB in, 5 floats out.
// R1: killed same-line atomicAdd fan-in (188us serialized chain).
// R2: LDS-staged coalesced float4 structure -> 70us, but 31.5KB LDS capped
//     residency at 5 blocks/CU (40% occ) -> latency-bound at 2.5 TB/s eff.
// R3 (FAILED): direct float2 loads lost coalescing + 784-block grid capped
//     occupancy at 26% -> 88us. Reverted.
// R4: R2 structure, CPB=128 -> 16KB LDS -> 8 blocks/CU (100% occupancy),
//     per-BOX threading (shfl_xor partner exchange) keeps all lanes busy.

#define NBATCH   4096
#define CELLS    (NBATCH * 14 * 14)     // 802816
#define THREADS  256
#define CPB      128                    // cells per block
#define NBLK     (CELLS / CPB)          // 6272
#define L_COORD  5.0f
#define L_NOOBJ  0.5f

__global__ __launch_bounds__(THREADS, 8) void yolo_main(
    const float* __restrict__ pred,    // [CELLS][30]
    const float* __restrict__ tbox,    // [CELLS][4]
    const float* __restrict__ tcls,    // [CELLS][20]
    const int*   __restrict__ objmap,  // [CELLS]
    float4*      __restrict__ part)    // [NBLK]
{
    __shared__ float lds_pred[CPB * 30];   // 15360 B
    __shared__ float lds_obj[CPB];         //   512 B
    __shared__ float red[4][4];

    const int tid  = threadIdx.x;
    const int blk  = blockIdx.x;
    const int base = blk * CPB;

    // ---- stage pred tile: 960 float4, fully coalesced ----
    {
        const float4* p4  = (const float4*)pred + (size_t)blk * (CPB * 30 / 4);
        float4*       lp4 = (float4*)lds_pred;
        #pragma unroll
        for (int i = tid; i < CPB * 30 / 4; i += THREADS)   // 4 iters, last partial
            lp4[i] = p4[i];
    }
    if (tid < CPB) lds_obj[tid] = objmap[base + tid] ? 1.0f : 0.0f;
    __syncthreads();

    float acc_reg = 0.f, acc_cont = 0.f, acc_noobj = 0.f, acc_cls = 0.f;

    // ---- cls pass: coalesced float4 stream over target_cls (640 float4) ----
    {
        const float4* c4 = (const float4*)tcls + (size_t)blk * (CPB * 20 / 4);
        #pragma unroll
        for (int i = tid; i < CPB * 20 / 4; i += THREADS) {  // 2-3 iters
            float4 t  = c4[i];
            int cell  = i / 5;                // 5 float4 per cell
            int ch0   = (i - cell * 5) * 4;
            float o   = lds_obj[cell];
            const float* pc = &lds_pred[cell * 30 + 10 + ch0];
            float d0 = pc[0] - t.x, d1 = pc[1] - t.y;
            float d2 = pc[2] - t.z, d3 = pc[3] - t.w;
            acc_cls += o * (d0*d0 + d1*d1 + d2*d2 + d3*d3);
        }
    }

    // ---- per-BOX pass: thread = (cell, box); partner exchange picks winner ----
    {
        const int cell = tid >> 1;
        const int box  = tid & 1;            // 0 -> box1, 1 -> box2
        const float* pp = &lds_pred[cell * 30 + box * 5];
        float x = pp[0], y = pp[1], w = pp[2], h = pp[3], conf = pp[4];
        float o  = lds_obj[cell];

        acc_noobj = (1.0f - o) * conf * conf;   // pair covers c1^2 + c2^2

        float4 tb = ((const float4*)tbox)[base + cell];  // pair-broadcast
        const float invS = 1.0f / 14.0f;

        // target xyxy
        float txc = tb.x * invS, tyc = tb.y * invS;
        float tx1 = txc - 0.5f * tb.z, ty1 = tyc - 0.5f * tb.w;
        float tx2 = txc + 0.5f * tb.z, ty2 = tyc + 0.5f * tb.w;
        float ta  = (tx2 - tx1) * (ty2 - ty1);

        // my box xyxy + iou
        float ax1 = x * invS - 0.5f * w, ay1 = y * invS - 0.5f * h;
        float ax2 = x * invS + 0.5f * w, ay2 = y * invS + 0.5f * h;
        float a1  = (ax2 - ax1) * (ay2 - ay1);
        float iw  = fmaxf(fminf(ax2, tx2) - fmaxf(ax1, tx1), 0.f);
        float ih  = fmaxf(fminf(ay2, ty2) - fmaxf(ay1, ty1), 0.f);
        float inter = iw * ih;
        float iou   = inter / (a1 + ta - inter);

        float iou_other = __shfl_xor(iou, 1);
        // reference: take1 = iou1 > iou2 (box1 wins strictly, else box2)
        bool win = (box == 0) ? (iou > iou_other) : !(iou_other > iou);

        if (win) {
            float dx = x - tb.x, dy = y - tb.y;
            float dw = sqrtf(w) - sqrtf(tb.z);
            float dh = sqrtf(h) - sqrtf(tb.w);
            acc_reg  = o * (dx*dx + dy*dy + dw*dw + dh*dh);
            float dc = conf - iou;
            acc_cont = o * dc * dc;
        }
    }

    // ---- block reduction: wave shuffle -> LDS -> one float4 store ----
    #pragma unroll
    for (int off = 32; off > 0; off >>= 1) {
        acc_reg   += __shfl_down(acc_reg,   off);
        acc_cont  += __shfl_down(acc_cont,  off);
        acc_noobj += __shfl_down(acc_noobj, off);
        acc_cls   += __shfl_down(acc_cls,   off);
    }
    const int wave = tid >> 6, lane = tid & 63;
    if (lane == 0) {
        red[wave][0] = acc_reg;
        red[wave][1] = acc_cont;
        red[wave][2] = acc_noobj;
        red[wave][3] = acc_cls;
    }
    __syncthreads();
    if (tid == 0) {
        float4 p;
        p.x = red[0][0] + red[1][0] + red[2][0] + red[3][0];
        p.y = red[0][1] + red[1][1] + red[2][1] + red[3][1];
        p.z = red[0][2] + red[1][2] + red[2][2] + red[3][2];
        p.w = red[0][3] + red[1][3] + red[2][3] + red[3][3];
        part[blk] = p;
    }
}

__global__ __launch_bounds__(1024) void yolo_reduce(
    const float4* __restrict__ part, float* __restrict__ out)
{
    __shared__ float red[16][4];
    float r = 0.f, c = 0.f, n = 0.f, cl = 0.f;
    for (int i = threadIdx.x; i < NBLK; i += 1024) {   // ~6 independent loads
        float4 p = part[i];
        r += p.x; c += p.y; n += p.z; cl += p.w;
    }
    #pragma unroll
    for (int off = 32; off > 0; off >>= 1) {
        r  += __shfl_down(r,  off);
        c  += __shfl_down(c,  off);
        n  += __shfl_down(n,  off);
        cl += __shfl_down(cl, off);
    }
    const int wave = threadIdx.x >> 6, lane = threadIdx.x & 63;
    if (lane == 0) {
        red[wave][0] = r; red[wave][1] = c; red[wave][2] = n; red[wave][3] = cl;
    }
    __syncthreads();
    if (threadIdx.x == 0) {
        float R = 0.f, C = 0.f, Nn = 0.f, Cl = 0.f;
        #pragma unroll
        for (int w = 0; w < 16; ++w) {
            R += red[w][0]; C += red[w][1]; Nn += red[w][2]; Cl += red[w][3];
        }
        const float invN = 1.0f / (float)NBATCH;
        float reg   = L_COORD * R  * invN;
        float cont  =           C  * invN;
        float noobj = L_NOOBJ * Nn * invN;
        float cls   =           Cl * invN;
        out[0] = reg + cont + noobj + cls;
        out[1] = reg;
        out[2] = cont;
        out[3] = noobj;
        out[4] = cls;
    }
}

extern "C" void kernel_launch(void* const* d_in, const int* in_sizes, int n_in,
                              void* d_out, int out_size, void* d_ws, size_t ws_size,
                              hipStream_t stream) {
    const float* pred   = (const float*)d_in[0];
    const float* tbox   = (const float*)d_in[1];
    const float* tcls   = (const float*)d_in[2];
    const int*   objmap = (const int*)  d_in[3];
    float4* part = (float4*)d_ws;      // NBLK * 16 B = 100 KB, every slot written
    float*  out  = (float*)d_out;

    yolo_main<<<NBLK, THREADS, 0, stream>>>(pred, tbox, tcls, objmap, part);
    yolo_reduce<<<1, 1024, 0, stream>>>(part, out);
}

// Round 5
// 195.724 us; speedup vs baseline: 1.1352x; 1.0613x over previous
//
#include <hip/hip_runtime.h>

// YOLO-v1 loss, N=4096, S=14 grid, 30 channels/cell. ~176 MB in, 5 floats out.
// R1: killed same-line atomicAdd fan-in (188us serialized chain) -> 70us.
// R2/R4: LDS-staged coalesced tiles; occupancy 40->67% changed nothing ->
//        limiter is the barrier-phased structure (gang vmcnt(0) drains), not
//        residency. Effective rate stuck at 2.55 TB/s.
// R5: barrier-free wave-autonomous streaming. Each WAVE owns a 3.84KB LDS
//     segment, processes 32-cell chunks grid-stride with same-wave
//     ds_write->waitcnt->ds_read (no __syncthreads in main loop). Plus
//     obj-gated tcls loads (15% density -> skip ~85% of 64MB tcls traffic).

#define NBATCH   4096
#define CELLS    (NBATCH * 14 * 14)     // 802816
#define THREADS  256
#define NBLK     2048                   // 8 blocks/CU exactly, persistent
#define NWAVES   (NBLK * 4)             // 8192
#define CHUNKS   (CELLS / 32)           // 25088 chunks of 32 cells
#define L_COORD  5.0f
#define L_NOOBJ  0.5f

__global__ __launch_bounds__(THREADS, 8) void yolo_main(
    const float* __restrict__ pred,    // [CELLS][30]
    const float* __restrict__ tbox,    // [CELLS][4]
    const float* __restrict__ tcls,    // [CELLS][20]
    const int*   __restrict__ objmap,  // [CELLS]
    float4*      __restrict__ part)    // [NBLK]
{
    __shared__ float lds[4 * 960];     // 3840 B per wave: 32 cells x 30 floats
    __shared__ float red[4][4];

    const int tid  = threadIdx.x;
    const int wv   = tid >> 6;
    const int lane = tid & 63;
    float* seg = &lds[wv * 960];

    // cls-pass lane->cell mapping (i = lane, lane+64, lane+128; cell = i/5)
    const int i1  = lane + 64, i2 = lane + 128;
    const int cc0 = lane / 5;
    const int cc1 = i1 / 5;
    const int cc2 = (lane < 32) ? (i2 / 5) : 0;
    const int ch0a = (lane - cc0 * 5) * 4;
    const int ch0b = (i1   - cc1 * 5) * 4;
    const int ch0c = (i2   - cc2 * 5) * 4;
    const int bcell = lane >> 1;       // per-box pairing: 2 lanes per cell
    const int box   = lane & 1;
    const float invS = 1.0f / 14.0f;

    float acc_reg = 0.f, acc_cont = 0.f, acc_noobj = 0.f, acc_cls = 0.f;

    const int gw0 = blockIdx.x * 4 + wv;
    for (int chunk = gw0; chunk < CHUNKS; chunk += NWAVES) {   // 3-4 iters
        const size_t cbase = (size_t)chunk * 32;

        // independent front-loaded reads: obj (2 lines/chunk) + tbox
        const int* ob = objmap + cbase;
        const int o0  = ob[cc0];
        const int o1  = ob[cc1];
        const int o2  = ob[cc2];
        const int obx = ob[bcell];
        const float4 tb = ((const float4*)tbox)[cbase + bcell];

        // stage pred chunk: 240 float4, fully coalesced, wave-private segment
        const float4* p4 = (const float4*)pred + (size_t)chunk * 240;
        float4* s4 = (float4*)seg;
        float4 v0 = p4[lane];
        float4 v1 = p4[i1];
        float4 v2 = p4[i2];
        float4 v3;
        if (lane < 48) v3 = p4[lane + 192];
        s4[lane] = v0;
        s4[i1]   = v1;
        s4[i2]   = v2;
        if (lane < 48) s4[lane + 192] = v3;

        __builtin_amdgcn_s_waitcnt(0);   // wave-local drain; NOT a barrier

        // ---- cls pass: tcls loads exec-masked on obj (15% density) ----
        {
            const float4* t4 = (const float4*)tcls + (size_t)chunk * 160;
            float cl = 0.f;
            if (o0) {
                float4 t = t4[lane];
                const float* pc = &seg[cc0 * 30 + 10 + ch0a];
                float d0 = pc[0]-t.x, d1 = pc[1]-t.y, d2 = pc[2]-t.z, d3 = pc[3]-t.w;
                cl += d0*d0 + d1*d1 + d2*d2 + d3*d3;
            }
            if (o1) {
                float4 t = t4[i1];
                const float* pc = &seg[cc1 * 30 + 10 + ch0b];
                float d0 = pc[0]-t.x, d1 = pc[1]-t.y, d2 = pc[2]-t.z, d3 = pc[3]-t.w;
                cl += d0*d0 + d1*d1 + d2*d2 + d3*d3;
            }
            if ((lane < 32) && o2) {
                float4 t = t4[i2];
                const float* pc = &seg[cc2 * 30 + 10 + ch0c];
                float d0 = pc[0]-t.x, d1 = pc[1]-t.y, d2 = pc[2]-t.z, d3 = pc[3]-t.w;
                cl += d0*d0 + d1*d1 + d2*d2 + d3*d3;
            }
            acc_cls += cl;
        }

        // ---- per-box pass: thread = (cell, box), partner via shfl_xor ----
        {
            const float* pp = &seg[bcell * 30 + box * 5];
            float x = pp[0], y = pp[1], w = pp[2], h = pp[3], conf = pp[4];

            if (!obx) acc_noobj += conf * conf;   // pair covers c1^2 + c2^2

            float txc = tb.x * invS, tyc = tb.y * invS;
            float tx1 = txc - 0.5f * tb.z, ty1 = tyc - 0.5f * tb.w;
            float tx2 = txc + 0.5f * tb.z, ty2 = tyc + 0.5f * tb.w;
            float ta  = (tx2 - tx1) * (ty2 - ty1);

            float ax1 = x * invS - 0.5f * w, ay1 = y * invS - 0.5f * h;
            float ax2 = x * invS + 0.5f * w, ay2 = y * invS + 0.5f * h;
            float a1  = (ax2 - ax1) * (ay2 - ay1);
            float iw  = fmaxf(fminf(ax2, tx2) - fmaxf(ax1, tx1), 0.f);
            float ih  = fmaxf(fminf(ay2, ty2) - fmaxf(ay1, ty1), 0.f);
            float inter = iw * ih;
            float iou   = inter / (a1 + ta - inter);

            float iou_other = __shfl_xor(iou, 1);
            // reference: take1 = iou1 > iou2
            bool win = (box == 0) ? (iou > iou_other) : !(iou_other > iou);

            if (win && obx) {
                float dx = x - tb.x, dy = y - tb.y;
                float dw = sqrtf(w) - sqrtf(tb.z);
                float dh = sqrtf(h) - sqrtf(tb.w);
                acc_reg  += dx*dx + dy*dy + dw*dw + dh*dh;
                float dc  = conf - iou;
                acc_cont += dc * dc;
            }
        }
    }

    // ---- final reduction (only barrier in the kernel) ----
    #pragma unroll
    for (int off = 32; off > 0; off >>= 1) {
        acc_reg   += __shfl_down(acc_reg,   off);
        acc_cont  += __shfl_down(acc_cont,  off);
        acc_noobj += __shfl_down(acc_noobj, off);
        acc_cls   += __shfl_down(acc_cls,   off);
    }
    if (lane == 0) {
        red[wv][0] = acc_reg;
        red[wv][1] = acc_cont;
        red[wv][2] = acc_noobj;
        red[wv][3] = acc_cls;
    }
    __syncthreads();
    if (tid == 0) {
        float4 p;
        p.x = red[0][0] + red[1][0] + red[2][0] + red[3][0];
        p.y = red[0][1] + red[1][1] + red[2][1] + red[3][1];
        p.z = red[0][2] + red[1][2] + red[2][2] + red[3][2];
        p.w = red[0][3] + red[1][3] + red[2][3] + red[3][3];
        part[blockIdx.x] = p;
    }
}

__global__ __launch_bounds__(1024) void yolo_reduce(
    const float4* __restrict__ part, float* __restrict__ out)
{
    __shared__ float red[16][4];
    float r = 0.f, c = 0.f, n = 0.f, cl = 0.f;
    #pragma unroll
    for (int i = threadIdx.x; i < NBLK; i += 1024) {   // exactly 2 loads
        float4 p = part[i];
        r += p.x; c += p.y; n += p.z; cl += p.w;
    }
    #pragma unroll
    for (int off = 32; off > 0; off >>= 1) {
        r  += __shfl_down(r,  off);
        c  += __shfl_down(c,  off);
        n  += __shfl_down(n,  off);
        cl += __shfl_down(cl, off);
    }
    const int wave = threadIdx.x >> 6, lane = threadIdx.x & 63;
    if (lane == 0) {
        red[wave][0] = r; red[wave][1] = c; red[wave][2] = n; red[wave][3] = cl;
    }
    __syncthreads();
    if (threadIdx.x == 0) {
        float R = 0.f, C = 0.f, Nn = 0.f, Cl = 0.f;
        #pragma unroll
        for (int w = 0; w < 16; ++w) {
            R += red[w][0]; C += red[w][1]; Nn += red[w][2]; Cl += red[w][3];
        }
        const float invN = 1.0f / (float)NBATCH;
        float reg   = L_COORD * R  * invN;
        float cont  =           C  * invN;
        float noobj = L_NOOBJ * Nn * invN;
        float cls   =           Cl * invN;
        out[0] = reg + cont + noobj + cls;
        out[1] = reg;
        out[2] = cont;
        out[3] = noobj;
        out[4] = cls;
    }
}

extern "C" void kernel_launch(void* const* d_in, const int* in_sizes, int n_in,
                              void* d_out, int out_size, void* d_ws, size_t ws_size,
                              hipStream_t stream) {
    const float* pred   = (const float*)d_in[0];
    const float* tbox   = (const float*)d_in[1];
    const float* tcls   = (const float*)d_in[2];
    const int*   objmap = (const int*)  d_in[3];
    float4* part = (float4*)d_ws;      // NBLK * 16 B = 32 KB, every slot written
    float*  out  = (float*)d_out;

    yolo_main<<<NBLK, THREADS, 0, stream>>>(pred, tbox, tcls, objmap, part);
    yolo_reduce<<<1, 1024, 0, stream>>>(part, out);
}